// Round 1
// baseline (1504.842 us; speedup 1.0000x reference)
//
#include <hip/hip_runtime.h>
#include <math.h>

// ---------------------------------------------------------------------------
// SimpleSelfAttention  B=4 S=2048 D=1024  fp32
//   Q = x @ Wq^T + bq ; K = x @ Wk^T + bk ; V = x @ Wv^T + bv
//   out = softmax(Q K^T / sqrt(D)) @ V
//
// Round 1: all-fp32 classic tiled SGEMM baseline (VALU-bound; no fp32 MFMA
// exists on CDNA4). Scores materialized in d_ws, chunked if ws is small.
// ---------------------------------------------------------------------------

#define BM 128
#define BN 128
#define BKd 16
#define TM 8
#define TN 8

// Generic 128x128x16 fp32 GEMM tile body.
//   C[m,n] = alpha * sum_k A[m,k] * B'[k,n] (+ bias[n])
//   TRANS_B = true : B is [N x K] row-major (B'[k,n] = B[n,k])   ("NT")
//   TRANS_B = false: B is [K x N] row-major                      ("NN")
// Grid: blockIdx.x = n-tile, blockIdx.y = m-tile. M,N multiples of 128,
// K multiple of 16 (all guaranteed here: 8192/2048/1024).
template <bool TRANS_B, bool HAS_BIAS>
__device__ __forceinline__ void gemm_body(
    const float* __restrict__ A, int lda,
    const float* __restrict__ B, int ldb,
    const float* __restrict__ bias,
    float* __restrict__ C, int ldc,
    int K, float alpha)
{
    __shared__ float As[BKd][BM + 4];   // k-major; +4 pad keeps float4 align
    __shared__ float Bs[BKd][BN + 4];

    const int tid = threadIdx.x;
    const int tx = tid & 15;    // n-direction (x8)
    const int ty = tid >> 4;    // m-direction (x8)
    const int m0 = blockIdx.y * BM;
    const int n0 = blockIdx.x * BN;

    // A tile: 128 rows x 16 k = 512 float4; thread -> rows (tid>>2, +64), col4 tid&3
    const int ra = tid >> 2;
    const int ca = (tid & 3) << 2;
    // B tile loader indices
    const int rb = TRANS_B ? ra : (tid >> 5);            // NT: 0..63 ; NN: 0..7
    const int cb = TRANS_B ? ca : ((tid & 31) << 2);     // NT: k-col ; NN: n-col

    float acc[TM][TN];
    #pragma unroll
    for (int i = 0; i < TM; ++i)
        #pragma unroll
        for (int j = 0; j < TN; ++j) acc[i][j] = 0.0f;

    const float* Aptr0 = A + (size_t)(m0 + ra) * lda + ca;
    const float* Aptr1 = A + (size_t)(m0 + ra + 64) * lda + ca;
    const float* Bptr0;
    const float* Bptr1;
    if (TRANS_B) {
        Bptr0 = B + (size_t)(n0 + rb) * ldb + cb;
        Bptr1 = B + (size_t)(n0 + rb + 64) * ldb + cb;
    } else {
        Bptr0 = B + (size_t)rb * ldb + n0 + cb;
        Bptr1 = B + (size_t)(rb + 8) * ldb + n0 + cb;
    }

    for (int k0 = 0; k0 < K; k0 += BKd) {
        // global loads issued before the barrier (overlap w/ prev inner loop)
        float4 a0 = *(const float4*)(Aptr0 + k0);
        float4 a1 = *(const float4*)(Aptr1 + k0);
        float4 b0, b1;
        if (TRANS_B) {
            b0 = *(const float4*)(Bptr0 + k0);
            b1 = *(const float4*)(Bptr1 + k0);
        } else {
            b0 = *(const float4*)(Bptr0 + (size_t)k0 * ldb);
            b1 = *(const float4*)(Bptr1 + (size_t)k0 * ldb);
        }
        __syncthreads();   // previous iteration's LDS readers done
        As[ca + 0][ra] = a0.x;  As[ca + 1][ra] = a0.y;
        As[ca + 2][ra] = a0.z;  As[ca + 3][ra] = a0.w;
        As[ca + 0][ra + 64] = a1.x;  As[ca + 1][ra + 64] = a1.y;
        As[ca + 2][ra + 64] = a1.z;  As[ca + 3][ra + 64] = a1.w;
        if (TRANS_B) {
            Bs[cb + 0][rb] = b0.x;  Bs[cb + 1][rb] = b0.y;
            Bs[cb + 2][rb] = b0.z;  Bs[cb + 3][rb] = b0.w;
            Bs[cb + 0][rb + 64] = b1.x;  Bs[cb + 1][rb + 64] = b1.y;
            Bs[cb + 2][rb + 64] = b1.z;  Bs[cb + 3][rb + 64] = b1.w;
        } else {
            *(float4*)&Bs[rb][cb]     = b0;
            *(float4*)&Bs[rb + 8][cb] = b1;
        }
        __syncthreads();
        #pragma unroll
        for (int kk = 0; kk < BKd; ++kk) {
            float a[TM], b[TN];
            *(float4*)&a[0] = *(const float4*)&As[kk][ty * TM];
            *(float4*)&a[4] = *(const float4*)&As[kk][ty * TM + 4];
            *(float4*)&b[0] = *(const float4*)&Bs[kk][tx * TN];
            *(float4*)&b[4] = *(const float4*)&Bs[kk][tx * TN + 4];
            #pragma unroll
            for (int i = 0; i < TM; ++i)
                #pragma unroll
                for (int j = 0; j < TN; ++j)
                    acc[i][j] = fmaf(a[i], b[j], acc[i][j]);
        }
    }

    float bcol[TN];
    if (HAS_BIAS) {
        *(float4*)&bcol[0] = *(const float4*)(bias + n0 + tx * TN);
        *(float4*)&bcol[4] = *(const float4*)(bias + n0 + tx * TN + 4);
    }
    #pragma unroll
    for (int i = 0; i < TM; ++i) {
        float* crow = C + (size_t)(m0 + ty * TM + i) * ldc + n0 + tx * TN;
        float4 r0, r1;
        r0.x = alpha * acc[i][0]; r0.y = alpha * acc[i][1];
        r0.z = alpha * acc[i][2]; r0.w = alpha * acc[i][3];
        r1.x = alpha * acc[i][4]; r1.y = alpha * acc[i][5];
        r1.z = alpha * acc[i][6]; r1.w = alpha * acc[i][7];
        if (HAS_BIAS) {
            r0.x += bcol[0]; r0.y += bcol[1]; r0.z += bcol[2]; r0.w += bcol[3];
            r1.x += bcol[4]; r1.y += bcol[5]; r1.z += bcol[6]; r1.w += bcol[7];
        }
        *(float4*)(crow)     = r0;
        *(float4*)(crow + 4) = r1;
    }
}

// grid: (D/BN, (B*S)/BM, 3) ; z selects Q/K/V projection
__global__ __launch_bounds__(256) void qkv_kernel(
    const float* __restrict__ x,
    const float* __restrict__ Wq, const float* __restrict__ bq,
    const float* __restrict__ Wk, const float* __restrict__ bk,
    const float* __restrict__ Wv, const float* __restrict__ bv,
    float* __restrict__ Q, float* __restrict__ Ko, float* __restrict__ Vo,
    int D)
{
    const float* W; const float* bias; float* C;
    if (blockIdx.z == 0)      { W = Wq; bias = bq; C = Q;  }
    else if (blockIdx.z == 1) { W = Wk; bias = bk; C = Ko; }
    else                      { W = Wv; bias = bv; C = Vo; }
    gemm_body<true, true>(x, D, W, D, bias, C, D, D, 1.0f);
}

// grid: (S/BN, R/BM, B) ; Sc chunk layout [B][R][S]
__global__ __launch_bounds__(256) void scores_kernel(
    const float* __restrict__ Q, const float* __restrict__ Km,
    float* __restrict__ Sc, int r0, int R, int S, int D, float alpha)
{
    const int b = blockIdx.z;
    gemm_body<true, false>(Q + (size_t)b * S * D + (size_t)r0 * D, D,
                           Km + (size_t)b * S * D, D, nullptr,
                           Sc + (size_t)b * R * S, S, D, alpha);
}

// grid: (D/BN, R/BM, B)
__global__ __launch_bounds__(256) void pv_kernel(
    const float* __restrict__ Sc, const float* __restrict__ V,
    float* __restrict__ Out, int r0, int R, int S, int D)
{
    const int b = blockIdx.z;
    gemm_body<false, false>(Sc + (size_t)b * R * S, S,
                            V + (size_t)b * S * D, D, nullptr,
                            Out + (size_t)b * S * D + (size_t)r0 * D, D, S, 1.0f);
}

// one block (256 threads) per row of 2048 scores; in-place softmax
__global__ __launch_bounds__(256) void softmax_kernel(float* __restrict__ Sc, int ncols)
{
    float* row = Sc + (size_t)blockIdx.x * ncols;
    const int tid = threadIdx.x;
    float v[8];
    *(float4*)&v[0] = *(const float4*)(row + tid * 8);
    *(float4*)&v[4] = *(const float4*)(row + tid * 8 + 4);

    float m = v[0];
    #pragma unroll
    for (int i = 1; i < 8; ++i) m = fmaxf(m, v[i]);
    #pragma unroll
    for (int o = 32; o > 0; o >>= 1) m = fmaxf(m, __shfl_xor(m, o));

    __shared__ float sm[4];
    __shared__ float ssum[4];
    const int wave = tid >> 6;
    if ((tid & 63) == 0) sm[wave] = m;
    __syncthreads();
    m = fmaxf(fmaxf(sm[0], sm[1]), fmaxf(sm[2], sm[3]));

    float s = 0.0f;
    #pragma unroll
    for (int i = 0; i < 8; ++i) { v[i] = __expf(v[i] - m); s += v[i]; }
    #pragma unroll
    for (int o = 32; o > 0; o >>= 1) s += __shfl_xor(s, o);
    if ((tid & 63) == 0) ssum[wave] = s;
    __syncthreads();
    s = ssum[0] + ssum[1] + ssum[2] + ssum[3];

    const float inv = 1.0f / s;
    #pragma unroll
    for (int i = 0; i < 8; ++i) v[i] *= inv;
    *(float4*)(row + tid * 8)     = *(float4*)&v[0];
    *(float4*)(row + tid * 8 + 4) = *(float4*)&v[4];
}

extern "C" void kernel_launch(void* const* d_in, const int* in_sizes, int n_in,
                              void* d_out, int out_size, void* d_ws, size_t ws_size,
                              hipStream_t stream)
{
    (void)in_sizes; (void)n_in; (void)out_size;
    const int Bn = 4, S = 2048, D = 1024;
    const float* x  = (const float*)d_in[0];
    const float* Wq = (const float*)d_in[1];
    const float* bq = (const float*)d_in[2];
    const float* Wk = (const float*)d_in[3];
    const float* bk = (const float*)d_in[4];
    const float* Wv = (const float*)d_in[5];
    const float* bv = (const float*)d_in[6];
    float* out = (float*)d_out;

    const size_t SD = (size_t)S * D;            // 2 Mi elements
    float* Q  = (float*)d_ws;                   // [B][S][D]
    float* Km = Q  + (size_t)Bn * SD;           // [B][S][D]
    float* Vm = Km + (size_t)Bn * SD;           // [B][S][D]
    float* Sc = Vm + (size_t)Bn * SD;           // [B][R][S] chunk

    // Pick q-row chunk R from available workspace (QKV needs 96 MiB; each
    // 128-row chunk of scores needs B*128*S*4 = 4 MiB; R=S wants 64 MiB).
    const long ws_f   = (long)(ws_size / 4);
    const long base_f = (long)3 * Bn * (long)SD;
    int R = BM;
    {
        long avail = ws_f - base_f;
        if (avail > 0) {
            long cap = avail / ((long)Bn * S);
            cap = (cap / BM) * BM;
            if (cap > S) cap = S;
            if (cap >= BM) R = (int)cap;
        }
    }

    // 1) QKV projections (fused, z = which projection)
    qkv_kernel<<<dim3(D / BN, (Bn * S) / BM, 3), 256, 0, stream>>>(
        x, Wq, bq, Wk, bk, Wv, bv, Q, Km, Vm, D);

    // 2) attention, chunked over q-rows
    const float scale = 1.0f / 32.0f;  // 1/sqrt(1024)
    for (int r0 = 0; r0 < S; r0 += R) {
        scores_kernel<<<dim3(S / BN, R / BM, Bn), 256, 0, stream>>>(
            Q, Km, Sc, r0, R, S, D, scale);
        softmax_kernel<<<dim3(Bn * R), 256, 0, stream>>>(Sc, S);
        pv_kernel<<<dim3(D / BN, R / BM, Bn), 256, 0, stream>>>(
            Sc, Vm, out, r0, R, S, D);
    }
}

// Round 2
// 862.096 us; speedup vs baseline: 1.7456x; 1.7456x over previous
//
#include <hip/hip_runtime.h>
#include <math.h>

// ---------------------------------------------------------------------------
// SimpleSelfAttention  B=4 S=2048 D=1024  fp32
// Round 2: split-bf16 MFMA path (x = hi+lo bf16; 3-term MFMA per product ->
// fp32-class accuracy at bf16 matrix-core rate). All three GEMMs share one
// NT k-major 128x128 MFMA core (16x16x32_bf16, global_load_lds width 16).
// Runtime fallback to the round-1 fp32 SGEMM path if ws_size < 140 MiB.
// ---------------------------------------------------------------------------

typedef short bf16x8 __attribute__((ext_vector_type(8)));
typedef float f32x4 __attribute__((ext_vector_type(4)));

__device__ __forceinline__ unsigned short f2bf(float f) {
    unsigned u = __float_as_uint(f);
    u += 0x7fffu + ((u >> 16) & 1u);          // RNE
    return (unsigned short)(u >> 16);
}
__device__ __forceinline__ float bf2f(unsigned short h) {
    return __uint_as_float(((unsigned)h) << 16);
}

__device__ __forceinline__ void glds16(const void* g, const void* l) {
    __builtin_amdgcn_global_load_lds(
        (const __attribute__((address_space(1))) void*)g,
        (__attribute__((address_space(3))) void*)l, 16, 0, 0);
}

// ---------------------------------------------------------------------------
// fp32 -> (hi,lo) bf16 planar split
// ---------------------------------------------------------------------------
__global__ __launch_bounds__(256) void split_kernel(
    const float* __restrict__ in, unsigned short* __restrict__ hi,
    unsigned short* __restrict__ lo, int n4)
{
    int i = blockIdx.x * 256 + threadIdx.x;
    if (i >= n4) return;
    float4 v = ((const float4*)in)[i];
    ushort4 h, l;
    h.x = f2bf(v.x); l.x = f2bf(v.x - bf2f(h.x));
    h.y = f2bf(v.y); l.y = f2bf(v.y - bf2f(h.y));
    h.z = f2bf(v.z); l.z = f2bf(v.z - bf2f(h.z));
    h.w = f2bf(v.w); l.w = f2bf(v.w - bf2f(h.w));
    ((ushort4*)hi)[i] = h;
    ((ushort4*)lo)[i] = l;
}

// ---------------------------------------------------------------------------
// Shared 128x128 NT split-bf16 MFMA core. A: [M][K] planar hi/lo (k-major),
// B: [N][K] planar hi/lo (k-major). K % 32 == 0. 256 threads = 4 waves (2x2),
// each wave 64x64 = 4x4 MFMA tiles. acc[i][j] in C/D layout.
// ---------------------------------------------------------------------------
__device__ __forceinline__ void mfma_core(
    const unsigned short* __restrict__ Ahi, const unsigned short* __restrict__ Alo, int lda,
    const unsigned short* __restrict__ Bhi, const unsigned short* __restrict__ Blo, int ldb,
    int K, int m0, int n0, unsigned short* sm, f32x4 acc[4][4])
{
    unsigned short* sAh = sm;            // [128][32]
    unsigned short* sAl = sm + 4096;
    unsigned short* sBh = sm + 8192;
    unsigned short* sBl = sm + 12288;

    const int tid  = threadIdx.x;
    const int lane = tid & 63;
    const int wave = tid >> 6;
    const int wm = (wave >> 1) * 64;
    const int wn = (wave & 1) * 64;
    const int lr = lane & 15;
    const int kq = lane >> 4;

    // staging: wave w covers tile rows [w*32, w*32+32)
    const int srow = wave * 32;
    const int grow = srow + (lane >> 2);
    const int gcol = (lane & 3) * 8;

    const unsigned short* gAh = Ahi + (size_t)(m0 + grow) * lda + gcol;
    const unsigned short* gAl = Alo + (size_t)(m0 + grow) * lda + gcol;
    const unsigned short* gBh = Bhi + (size_t)(n0 + grow) * ldb + gcol;
    const unsigned short* gBl = Blo + (size_t)(n0 + grow) * ldb + gcol;
    const size_t rsA = (size_t)16 * lda;
    const size_t rsB = (size_t)16 * ldb;

    unsigned short* lAh = sAh + srow * 32;
    unsigned short* lAl = sAl + srow * 32;
    unsigned short* lBh = sBh + srow * 32;
    unsigned short* lBl = sBl + srow * 32;

    for (int k0 = 0; k0 < K; k0 += 32) {
        glds16(gAh + k0,       lAh);
        glds16(gAh + k0 + rsA, lAh + 512);
        glds16(gAl + k0,       lAl);
        glds16(gAl + k0 + rsA, lAl + 512);
        glds16(gBh + k0,       lBh);
        glds16(gBh + k0 + rsB, lBh + 512);
        glds16(gBl + k0,       lBl);
        glds16(gBl + k0 + rsB, lBl + 512);
        __syncthreads();   // drains vmcnt: LDS tiles ready

        bf16x8 ah[4], al[4], bh[4], bl[4];
        #pragma unroll
        for (int i = 0; i < 4; ++i) {
            const int ra = wm + i * 16 + lr;
            const int rb = wn + i * 16 + lr;
            ah[i] = *(const bf16x8*)&sAh[ra * 32 + kq * 8];
            al[i] = *(const bf16x8*)&sAl[ra * 32 + kq * 8];
            bh[i] = *(const bf16x8*)&sBh[rb * 32 + kq * 8];
            bl[i] = *(const bf16x8*)&sBl[rb * 32 + kq * 8];
        }
        #pragma unroll
        for (int i = 0; i < 4; ++i)
            #pragma unroll
            for (int j = 0; j < 4; ++j) {
                acc[i][j] = __builtin_amdgcn_mfma_f32_16x16x32_bf16(ah[i], bh[j], acc[i][j], 0, 0, 0);
                acc[i][j] = __builtin_amdgcn_mfma_f32_16x16x32_bf16(ah[i], bl[j], acc[i][j], 0, 0, 0);
                acc[i][j] = __builtin_amdgcn_mfma_f32_16x16x32_bf16(al[i], bh[j], acc[i][j], 0, 0, 0);
            }
        __syncthreads();   // readers done before next stage overwrites
    }
}

// grid (D/128, (B*S)/128, 3)
__global__ __launch_bounds__(256) void qkv_mfma_kernel(
    const unsigned short* __restrict__ xhi, const unsigned short* __restrict__ xlo,
    const unsigned short* __restrict__ Whi, const unsigned short* __restrict__ Wlo, // [3][D*D]
    const float* __restrict__ bq, const float* __restrict__ bk, const float* __restrict__ bv,
    unsigned short* __restrict__ Qhi, unsigned short* __restrict__ Qlo,
    unsigned short* __restrict__ Khi, unsigned short* __restrict__ Klo,
    unsigned short* __restrict__ Vthi, unsigned short* __restrict__ Vtlo)
{
    __shared__ __align__(16) unsigned short smem[4 * 4096];
    const int z  = blockIdx.z;
    const int m0 = blockIdx.y * 128;
    const int n0 = blockIdx.x * 128;

    f32x4 acc[4][4];
    #pragma unroll
    for (int i = 0; i < 4; ++i)
        #pragma unroll
        for (int j = 0; j < 4; ++j) acc[i][j] = (f32x4){0.f, 0.f, 0.f, 0.f};

    const size_t wo = (size_t)z * 1024 * 1024;
    mfma_core(xhi, xlo, 1024, Whi + wo, Wlo + wo, 1024, 1024, m0, n0, smem, acc);

    const float* bias = (z == 0) ? bq : (z == 1) ? bk : bv;
    const int lane = threadIdx.x & 63;
    const int wave = threadIdx.x >> 6;
    const int wm = (wave >> 1) * 64;
    const int wn = (wave & 1) * 64;
    const int col  = lane & 15;
    const int quad = lane >> 4;

    #pragma unroll
    for (int j = 0; j < 4; ++j) {
        const int gn = n0 + wn + j * 16 + col;
        const float bb = bias[gn];
        #pragma unroll
        for (int i = 0; i < 4; ++i) {
            #pragma unroll
            for (int r = 0; r < 4; ++r) {
                const int gm = m0 + wm + i * 16 + quad * 4 + r;
                const float v = acc[i][j][r] + bb;
                const unsigned short h = f2bf(v);
                const unsigned short l = f2bf(v - bf2f(h));
                if (z == 0) {
                    const size_t idx = (size_t)gm * 1024 + gn;
                    Qhi[idx] = h; Qlo[idx] = l;
                } else if (z == 1) {
                    const size_t idx = (size_t)gm * 1024 + gn;
                    Khi[idx] = h; Klo[idx] = l;
                } else {
                    const int b = gm >> 11, t = gm & 2047;
                    const size_t idx = (size_t)b * (1024 * 2048) + (size_t)gn * 2048 + t;
                    Vthi[idx] = h; Vtlo[idx] = l;
                }
            }
        }
    }
}

// grid (S/128, R/128, B); Sc chunk [B][R][S] fp32
__global__ __launch_bounds__(256) void scores_mfma_kernel(
    const unsigned short* __restrict__ Qhi, const unsigned short* __restrict__ Qlo,
    const unsigned short* __restrict__ Khi, const unsigned short* __restrict__ Klo,
    float* __restrict__ Sc, int r0, int R, float alpha)
{
    __shared__ __align__(16) unsigned short smem[4 * 4096];
    const int b  = blockIdx.z;
    const int m0 = blockIdx.y * 128;
    const int n0 = blockIdx.x * 128;

    f32x4 acc[4][4];
    #pragma unroll
    for (int i = 0; i < 4; ++i)
        #pragma unroll
        for (int j = 0; j < 4; ++j) acc[i][j] = (f32x4){0.f, 0.f, 0.f, 0.f};

    const size_t ao = ((size_t)b * 2048 + r0) * 1024;
    const size_t bo = (size_t)b * 2048 * 1024;
    mfma_core(Qhi + ao, Qlo + ao, 1024, Khi + bo, Klo + bo, 1024, 1024, m0, n0, smem, acc);

    const int lane = threadIdx.x & 63;
    const int wave = threadIdx.x >> 6;
    const int wm = (wave >> 1) * 64;
    const int wn = (wave & 1) * 64;
    const int col  = lane & 15;
    const int quad = lane >> 4;
    float* C = Sc + (size_t)b * R * 2048;

    #pragma unroll
    for (int i = 0; i < 4; ++i)
        #pragma unroll
        for (int r = 0; r < 4; ++r) {
            const int gm = m0 + wm + i * 16 + quad * 4 + r;
            #pragma unroll
            for (int j = 0; j < 4; ++j) {
                const int gn = n0 + wn + j * 16 + col;
                C[(size_t)gm * 2048 + gn] = alpha * acc[i][j][r];
            }
        }
}

// grid (D/128, R/128, B); out [B][S][D] fp32
__global__ __launch_bounds__(256) void pv_mfma_kernel(
    const unsigned short* __restrict__ Phi, const unsigned short* __restrict__ Plo,
    const unsigned short* __restrict__ Vthi, const unsigned short* __restrict__ Vtlo,
    float* __restrict__ out, int r0, int R)
{
    __shared__ __align__(16) unsigned short smem[4 * 4096];
    const int b  = blockIdx.z;
    const int m0 = blockIdx.y * 128;
    const int n0 = blockIdx.x * 128;

    f32x4 acc[4][4];
    #pragma unroll
    for (int i = 0; i < 4; ++i)
        #pragma unroll
        for (int j = 0; j < 4; ++j) acc[i][j] = (f32x4){0.f, 0.f, 0.f, 0.f};

    const size_t ao = (size_t)b * R * 2048;
    const size_t bo = (size_t)b * 1024 * 2048;
    mfma_core(Phi + ao, Plo + ao, 2048, Vthi + bo, Vtlo + bo, 2048, 2048, m0, n0, smem, acc);

    const int lane = threadIdx.x & 63;
    const int wave = threadIdx.x >> 6;
    const int wm = (wave >> 1) * 64;
    const int wn = (wave & 1) * 64;
    const int col  = lane & 15;
    const int quad = lane >> 4;
    float* C = out + (size_t)b * 2048 * 1024 + (size_t)r0 * 1024;

    #pragma unroll
    for (int i = 0; i < 4; ++i)
        #pragma unroll
        for (int r = 0; r < 4; ++r) {
            const int gm = m0 + wm + i * 16 + quad * 4 + r;
            #pragma unroll
            for (int j = 0; j < 4; ++j) {
                const int gn = n0 + wn + j * 16 + col;
                C[(size_t)gm * 1024 + gn] = acc[i][j][r];
            }
        }
}

// one block per score row; reads fp32 Sc, writes split-bf16 P planes
__global__ __launch_bounds__(256) void softmax_split_kernel(
    const float* __restrict__ Sc, unsigned short* __restrict__ Phi,
    unsigned short* __restrict__ Plo)
{
    const size_t base = (size_t)blockIdx.x * 2048;
    const int tid = threadIdx.x;
    float v[8];
    *(float4*)&v[0] = *(const float4*)(Sc + base + tid * 8);
    *(float4*)&v[4] = *(const float4*)(Sc + base + tid * 8 + 4);

    float m = v[0];
    #pragma unroll
    for (int i = 1; i < 8; ++i) m = fmaxf(m, v[i]);
    #pragma unroll
    for (int o = 32; o > 0; o >>= 1) m = fmaxf(m, __shfl_xor(m, o));

    __shared__ float sm[4], ssum[4];
    const int wave = tid >> 6;
    if ((tid & 63) == 0) sm[wave] = m;
    __syncthreads();
    m = fmaxf(fmaxf(sm[0], sm[1]), fmaxf(sm[2], sm[3]));

    float s = 0.0f;
    #pragma unroll
    for (int i = 0; i < 8; ++i) { v[i] = __expf(v[i] - m); s += v[i]; }
    #pragma unroll
    for (int o = 32; o > 0; o >>= 1) s += __shfl_xor(s, o);
    if ((tid & 63) == 0) ssum[wave] = s;
    __syncthreads();
    s = ssum[0] + ssum[1] + ssum[2] + ssum[3];
    const float inv = 1.0f / s;

    ushort4 h0, h1, l0, l1;
    float p;
    p = v[0] * inv; h0.x = f2bf(p); l0.x = f2bf(p - bf2f(h0.x));
    p = v[1] * inv; h0.y = f2bf(p); l0.y = f2bf(p - bf2f(h0.y));
    p = v[2] * inv; h0.z = f2bf(p); l0.z = f2bf(p - bf2f(h0.z));
    p = v[3] * inv; h0.w = f2bf(p); l0.w = f2bf(p - bf2f(h0.w));
    p = v[4] * inv; h1.x = f2bf(p); l1.x = f2bf(p - bf2f(h1.x));
    p = v[5] * inv; h1.y = f2bf(p); l1.y = f2bf(p - bf2f(h1.y));
    p = v[6] * inv; h1.z = f2bf(p); l1.z = f2bf(p - bf2f(h1.z));
    p = v[7] * inv; h1.w = f2bf(p); l1.w = f2bf(p - bf2f(h1.w));
    *(ushort4*)(Phi + base + tid * 8)     = h0;
    *(ushort4*)(Phi + base + tid * 8 + 4) = h1;
    *(ushort4*)(Plo + base + tid * 8)     = l0;
    *(ushort4*)(Plo + base + tid * 8 + 4) = l1;
}

// ===========================================================================
// Round-1 fp32 fallback (used only if ws_size < fast-path footprint)
// ===========================================================================
#define BM 128
#define BN 128
#define BKd 16
#define TM 8
#define TN 8

template <bool TRANS_B, bool HAS_BIAS>
__device__ __forceinline__ void gemm_body(
    const float* __restrict__ A, int lda,
    const float* __restrict__ B, int ldb,
    const float* __restrict__ bias,
    float* __restrict__ C, int ldc,
    int K, float alpha)
{
    __shared__ float As[BKd][BM + 4];
    __shared__ float Bs[BKd][BN + 4];

    const int tid = threadIdx.x;
    const int tx = tid & 15;
    const int ty = tid >> 4;
    const int m0 = blockIdx.y * BM;
    const int n0 = blockIdx.x * BN;
    const int ra = tid >> 2;
    const int ca = (tid & 3) << 2;
    const int rb = TRANS_B ? ra : (tid >> 5);
    const int cb = TRANS_B ? ca : ((tid & 31) << 2);

    float acc[TM][TN];
    #pragma unroll
    for (int i = 0; i < TM; ++i)
        #pragma unroll
        for (int j = 0; j < TN; ++j) acc[i][j] = 0.0f;

    const float* Aptr0 = A + (size_t)(m0 + ra) * lda + ca;
    const float* Aptr1 = A + (size_t)(m0 + ra + 64) * lda + ca;
    const float* Bptr0;
    const float* Bptr1;
    if (TRANS_B) {
        Bptr0 = B + (size_t)(n0 + rb) * ldb + cb;
        Bptr1 = B + (size_t)(n0 + rb + 64) * ldb + cb;
    } else {
        Bptr0 = B + (size_t)rb * ldb + n0 + cb;
        Bptr1 = B + (size_t)(rb + 8) * ldb + n0 + cb;
    }

    for (int k0 = 0; k0 < K; k0 += BKd) {
        float4 a0 = *(const float4*)(Aptr0 + k0);
        float4 a1 = *(const float4*)(Aptr1 + k0);
        float4 b0, b1;
        if (TRANS_B) {
            b0 = *(const float4*)(Bptr0 + k0);
            b1 = *(const float4*)(Bptr1 + k0);
        } else {
            b0 = *(const float4*)(Bptr0 + (size_t)k0 * ldb);
            b1 = *(const float4*)(Bptr1 + (size_t)k0 * ldb);
        }
        __syncthreads();
        As[ca + 0][ra] = a0.x;  As[ca + 1][ra] = a0.y;
        As[ca + 2][ra] = a0.z;  As[ca + 3][ra] = a0.w;
        As[ca + 0][ra + 64] = a1.x;  As[ca + 1][ra + 64] = a1.y;
        As[ca + 2][ra + 64] = a1.z;  As[ca + 3][ra + 64] = a1.w;
        if (TRANS_B) {
            Bs[cb + 0][rb] = b0.x;  Bs[cb + 1][rb] = b0.y;
            Bs[cb + 2][rb] = b0.z;  Bs[cb + 3][rb] = b0.w;
            Bs[cb + 0][rb + 64] = b1.x;  Bs[cb + 1][rb + 64] = b1.y;
            Bs[cb + 2][rb + 64] = b1.z;  Bs[cb + 3][rb + 64] = b1.w;
        } else {
            *(float4*)&Bs[rb][cb]     = b0;
            *(float4*)&Bs[rb + 8][cb] = b1;
        }
        __syncthreads();
        #pragma unroll
        for (int kk = 0; kk < BKd; ++kk) {
            float a[TM], b[TN];
            *(float4*)&a[0] = *(const float4*)&As[kk][ty * TM];
            *(float4*)&a[4] = *(const float4*)&As[kk][ty * TM + 4];
            *(float4*)&b[0] = *(const float4*)&Bs[kk][tx * TN];
            *(float4*)&b[4] = *(const float4*)&Bs[kk][tx * TN + 4];
            #pragma unroll
            for (int i = 0; i < TM; ++i)
                #pragma unroll
                for (int j = 0; j < TN; ++j)
                    acc[i][j] = fmaf(a[i], b[j], acc[i][j]);
        }
    }

    float bcol[TN];
    if (HAS_BIAS) {
        *(float4*)&bcol[0] = *(const float4*)(bias + n0 + tx * TN);
        *(float4*)&bcol[4] = *(const float4*)(bias + n0 + tx * TN + 4);
    }
    #pragma unroll
    for (int i = 0; i < TM; ++i) {
        float* crow = C + (size_t)(m0 + ty * TM + i) * ldc + n0 + tx * TN;
        float4 r0, r1;
        r0.x = alpha * acc[i][0]; r0.y = alpha * acc[i][1];
        r0.z = alpha * acc[i][2]; r0.w = alpha * acc[i][3];
        r1.x = alpha * acc[i][4]; r1.y = alpha * acc[i][5];
        r1.z = alpha * acc[i][6]; r1.w = alpha * acc[i][7];
        if (HAS_BIAS) {
            r0.x += bcol[0]; r0.y += bcol[1]; r0.z += bcol[2]; r0.w += bcol[3];
            r1.x += bcol[4]; r1.y += bcol[5]; r1.z += bcol[6]; r1.w += bcol[7];
        }
        *(float4*)(crow)     = r0;
        *(float4*)(crow + 4) = r1;
    }
}

__global__ __launch_bounds__(256) void qkv_kernel(
    const float* __restrict__ x,
    const float* __restrict__ Wq, const float* __restrict__ bq,
    const float* __restrict__ Wk, const float* __restrict__ bk,
    const float* __restrict__ Wv, const float* __restrict__ bv,
    float* __restrict__ Q, float* __restrict__ Ko, float* __restrict__ Vo,
    int D)
{
    const float* W; const float* bias; float* C;
    if (blockIdx.z == 0)      { W = Wq; bias = bq; C = Q;  }
    else if (blockIdx.z == 1) { W = Wk; bias = bk; C = Ko; }
    else                      { W = Wv; bias = bv; C = Vo; }
    gemm_body<true, true>(x, D, W, D, bias, C, D, D, 1.0f);
}

__global__ __launch_bounds__(256) void scores_kernel(
    const float* __restrict__ Q, const float* __restrict__ Km,
    float* __restrict__ Sc, int r0, int R, int S, int D, float alpha)
{
    const int b = blockIdx.z;
    gemm_body<true, false>(Q + (size_t)b * S * D + (size_t)r0 * D, D,
                           Km + (size_t)b * S * D, D, nullptr,
                           Sc + (size_t)b * R * S, S, D, alpha);
}

__global__ __launch_bounds__(256) void pv_kernel(
    const float* __restrict__ Sc, const float* __restrict__ V,
    float* __restrict__ Out, int r0, int R, int S, int D)
{
    const int b = blockIdx.z;
    gemm_body<false, false>(Sc + (size_t)b * R * S, S,
                            V + (size_t)b * S * D, D, nullptr,
                            Out + (size_t)b * S * D + (size_t)r0 * D, D, S, 1.0f);
}

__global__ __launch_bounds__(256) void softmax_kernel(float* __restrict__ Sc, int ncols)
{
    float* row = Sc + (size_t)blockIdx.x * ncols;
    const int tid = threadIdx.x;
    float v[8];
    *(float4*)&v[0] = *(const float4*)(row + tid * 8);
    *(float4*)&v[4] = *(const float4*)(row + tid * 8 + 4);

    float m = v[0];
    #pragma unroll
    for (int i = 1; i < 8; ++i) m = fmaxf(m, v[i]);
    #pragma unroll
    for (int o = 32; o > 0; o >>= 1) m = fmaxf(m, __shfl_xor(m, o));

    __shared__ float sm[4];
    __shared__ float ssum[4];
    const int wave = tid >> 6;
    if ((tid & 63) == 0) sm[wave] = m;
    __syncthreads();
    m = fmaxf(fmaxf(sm[0], sm[1]), fmaxf(sm[2], sm[3]));

    float s = 0.0f;
    #pragma unroll
    for (int i = 0; i < 8; ++i) { v[i] = __expf(v[i] - m); s += v[i]; }
    #pragma unroll
    for (int o = 32; o > 0; o >>= 1) s += __shfl_xor(s, o);
    if ((tid & 63) == 0) ssum[wave] = s;
    __syncthreads();
    s = ssum[0] + ssum[1] + ssum[2] + ssum[3];

    const float inv = 1.0f / s;
    #pragma unroll
    for (int i = 0; i < 8; ++i) v[i] *= inv;
    *(float4*)(row + tid * 8)     = *(float4*)&v[0];
    *(float4*)(row + tid * 8 + 4) = *(float4*)&v[4];
}

// ===========================================================================
extern "C" void kernel_launch(void* const* d_in, const int* in_sizes, int n_in,
                              void* d_out, int out_size, void* d_ws, size_t ws_size,
                              hipStream_t stream)
{
    (void)in_sizes; (void)n_in; (void)out_size;
    const int Bn = 4, S = 2048, D = 1024;
    const float* x  = (const float*)d_in[0];
    const float* Wq = (const float*)d_in[1];
    const float* bq = (const float*)d_in[2];
    const float* Wk = (const float*)d_in[3];
    const float* bk = (const float*)d_in[4];
    const float* Wv = (const float*)d_in[5];
    const float* bv = (const float*)d_in[6];
    float* out = (float*)d_out;

    const size_t MB = 1024 * 1024;
    const size_t need_fast = 140 * MB;

    if (ws_size >= need_fast) {
        // ---------------- fast split-bf16 MFMA path ----------------
        char* w = (char*)d_ws;
        unsigned short* xhi  = (unsigned short*)(w + 0 * MB);    // 16 MiB
        unsigned short* xlo  = (unsigned short*)(w + 16 * MB);   // 16 MiB
        unsigned short* Whi3 = (unsigned short*)(w + 32 * MB);   // 6 MiB  [3][D*D]
        unsigned short* Wlo3 = (unsigned short*)(w + 38 * MB);   // 6 MiB
        unsigned short* Qhi  = (unsigned short*)(w + 44 * MB);
        unsigned short* Qlo  = (unsigned short*)(w + 60 * MB);
        unsigned short* Khi  = (unsigned short*)(w + 76 * MB);
        unsigned short* Klo  = (unsigned short*)(w + 92 * MB);
        unsigned short* Vthi = (unsigned short*)(w + 108 * MB);
        unsigned short* Vtlo = (unsigned short*)(w + 124 * MB);
        // chunk region aliases [0, 44 MiB) — x/W splits are dead post-QKV
        const int R = 512;                                       // 4 chunks
        float*          Sc   = (float*)(w + 0 * MB);             // 16 MiB
        unsigned short* Phi  = (unsigned short*)(w + 16 * MB);   // 8 MiB
        unsigned short* Plo  = (unsigned short*)(w + 24 * MB);   // 8 MiB

        // 1) splits
        split_kernel<<<dim3((Bn * S * D / 4 + 255) / 256), 256, 0, stream>>>(
            x, xhi, xlo, Bn * S * D / 4);
        split_kernel<<<dim3((D * D / 4 + 255) / 256), 256, 0, stream>>>(
            Wq, Whi3 + 0 * D * D, Wlo3 + 0 * D * D, D * D / 4);
        split_kernel<<<dim3((D * D / 4 + 255) / 256), 256, 0, stream>>>(
            Wk, Whi3 + 1 * D * D, Wlo3 + 1 * D * D, D * D / 4);
        split_kernel<<<dim3((D * D / 4 + 255) / 256), 256, 0, stream>>>(
            Wv, Whi3 + 2 * D * D, Wlo3 + 2 * D * D, D * D / 4);

        // 2) QKV projections
        qkv_mfma_kernel<<<dim3(D / 128, (Bn * S) / 128, 3), 256, 0, stream>>>(
            xhi, xlo, Whi3, Wlo3, bq, bk, bv, Qhi, Qlo, Khi, Klo, Vthi, Vtlo);

        // 3) attention, chunked over q-rows
        const float scale = 1.0f / 32.0f;
        for (int r0 = 0; r0 < S; r0 += R) {
            scores_mfma_kernel<<<dim3(S / 128, R / 128, Bn), 256, 0, stream>>>(
                Qhi, Qlo, Khi, Klo, Sc, r0, R, scale);
            softmax_split_kernel<<<dim3(Bn * R), 256, 0, stream>>>(Sc, Phi, Plo);
            pv_mfma_kernel<<<dim3(D / 128, R / 128, Bn), 256, 0, stream>>>(
                Phi, Plo, Vthi, Vtlo, out, r0, R);
        }
    } else {
        // ---------------- fp32 fallback (round-1) ----------------
        const size_t SD = (size_t)S * D;
        float* Q  = (float*)d_ws;
        float* Km = Q  + (size_t)Bn * SD;
        float* Vm = Km + (size_t)Bn * SD;
        float* Sc = Vm + (size_t)Bn * SD;

        const long ws_f   = (long)(ws_size / 4);
        const long base_f = (long)3 * Bn * (long)SD;
        int R = BM;
        {
            long avail = ws_f - base_f;
            if (avail > 0) {
                long cap = avail / ((long)Bn * S);
                cap = (cap / BM) * BM;
                if (cap > S) cap = S;
                if (cap >= BM) R = (int)cap;
            }
        }

        qkv_kernel<<<dim3(D / BN, (Bn * S) / BM, 3), 256, 0, stream>>>(
            x, Wq, bq, Wk, bk, Wv, bv, Q, Km, Vm, D);

        const float scale = 1.0f / 32.0f;
        for (int r0 = 0; r0 < S; r0 += R) {
            scores_kernel<<<dim3(S / BN, R / BM, Bn), 256, 0, stream>>>(
                Q, Km, Sc, r0, R, S, D, scale);
            softmax_kernel<<<dim3(Bn * R), 256, 0, stream>>>(Sc, S);
            pv_kernel<<<dim3(D / BN, R / BM, Bn), 256, 0, stream>>>(
                Sc, Vm, out, r0, R, S, D);
        }
    }
}

// Round 3
// 446.879 us; speedup vs baseline: 3.3674x; 1.9291x over previous
//
#include <hip/hip_runtime.h>
#include <math.h>

// ---------------------------------------------------------------------------
// SimpleSelfAttention  B=4 S=2048 D=1024  fp32
// Round 3: fp16 asymmetric 2-term MFMA scheme.
//   A operand: single fp16 (truncation err ~2^-12 * sqrt(K) ~ 1e-4/stage)
//   B operand: hi+lo fp16 pair -> 2 MFMAs per product (was 3 bf16 terms).
//   W pre-scaled x32 (keeps W-lo out of fp16 denormal range), /32 in epilogue.
//   P pre-scaled x512 (keeps small probs normal),           /512 in epilogue.
// Attention chunk R adaptive: full 2048 if ws >= 172 MiB, else 1024/512.
// ---------------------------------------------------------------------------

typedef _Float16 f16;
typedef _Float16 f16x8 __attribute__((ext_vector_type(8)));
typedef _Float16 f16x4 __attribute__((ext_vector_type(4)));
typedef float f32x4 __attribute__((ext_vector_type(4)));

__device__ __forceinline__ void glds16(const void* g, const void* l) {
    __builtin_amdgcn_global_load_lds(
        (const __attribute__((address_space(1))) void*)g,
        (__attribute__((address_space(3))) void*)l, 16, 0, 0);
}

// ---------------------------------------------------------------------------
// fp32 -> fp16 single plane (for x)
// ---------------------------------------------------------------------------
__global__ __launch_bounds__(256) void split1_kernel(
    const float* __restrict__ in, f16* __restrict__ hi, int n4)
{
    int i = blockIdx.x * 256 + threadIdx.x;
    if (i >= n4) return;
    float4 v = ((const float4*)in)[i];
    f16x4 h = { (f16)v.x, (f16)v.y, (f16)v.z, (f16)v.w };
    ((f16x4*)hi)[i] = h;
}

// fp32 * scale -> fp16 hi + fp16 lo (for W; scale=32 keeps lo normal-range)
__global__ __launch_bounds__(256) void split2_kernel(
    const float* __restrict__ in, f16* __restrict__ hi, f16* __restrict__ lo,
    int n4, float scale)
{
    int i = blockIdx.x * 256 + threadIdx.x;
    if (i >= n4) return;
    float4 v = ((const float4*)in)[i];
    float a0 = v.x * scale, a1 = v.y * scale, a2 = v.z * scale, a3 = v.w * scale;
    f16 h0 = (f16)a0, h1 = (f16)a1, h2 = (f16)a2, h3 = (f16)a3;
    f16x4 h = { h0, h1, h2, h3 };
    f16x4 l = { (f16)(a0 - (float)h0), (f16)(a1 - (float)h1),
                (f16)(a2 - (float)h2), (f16)(a3 - (float)h3) };
    ((f16x4*)hi)[i] = h;
    ((f16x4*)lo)[i] = l;
}

// ---------------------------------------------------------------------------
// 128x128 NT fp16 MFMA core, asymmetric 2-term:
//   C += A * (Bh + Bl)^T     A:[M][K] single plane, B:[N][K] hi/lo planes
// 256 threads = 4 waves (2x2), each wave 64x64 = 4x4 16x16 tiles.
// LDS 24 KiB (3 planes of 128x32 fp16), K % 32 == 0.
// ---------------------------------------------------------------------------
__device__ __forceinline__ void mfma_core2(
    const f16* __restrict__ A, int lda,
    const f16* __restrict__ Bh, const f16* __restrict__ Bl, int ldb,
    int K, int m0, int n0, f16* sm, f32x4 acc[4][4])
{
    f16* sA  = sm;           // [128][32]
    f16* sBh = sm + 4096;
    f16* sBl = sm + 8192;

    const int tid  = threadIdx.x;
    const int lane = tid & 63;
    const int wave = tid >> 6;
    const int wm = (wave >> 1) * 64;
    const int wn = (wave & 1) * 64;
    const int lr = lane & 15;
    const int kq = lane >> 4;

    // staging: wave w covers tile rows [w*32, w*32+32)
    const int srow = wave * 32;
    const int grow = srow + (lane >> 2);
    const int gcol = (lane & 3) * 8;

    const f16* gA  = A  + (size_t)(m0 + grow) * lda + gcol;
    const f16* gBh = Bh + (size_t)(n0 + grow) * ldb + gcol;
    const f16* gBl = Bl + (size_t)(n0 + grow) * ldb + gcol;
    const size_t rsA = (size_t)16 * lda;
    const size_t rsB = (size_t)16 * ldb;

    f16* lA  = sA  + srow * 32;
    f16* lBh = sBh + srow * 32;
    f16* lBl = sBl + srow * 32;

    for (int k0 = 0; k0 < K; k0 += 32) {
        glds16(gA + k0,        lA);
        glds16(gA + k0 + rsA,  lA + 512);
        glds16(gBh + k0,       lBh);
        glds16(gBh + k0 + rsB, lBh + 512);
        glds16(gBl + k0,       lBl);
        glds16(gBl + k0 + rsB, lBl + 512);
        __syncthreads();   // drains vmcnt: LDS tiles ready

        f16x8 a[4], bh[4], bl[4];
        #pragma unroll
        for (int i = 0; i < 4; ++i) {
            a[i]  = *(const f16x8*)&sA [(wm + i * 16 + lr) * 32 + kq * 8];
            bh[i] = *(const f16x8*)&sBh[(wn + i * 16 + lr) * 32 + kq * 8];
            bl[i] = *(const f16x8*)&sBl[(wn + i * 16 + lr) * 32 + kq * 8];
        }
        #pragma unroll
        for (int i = 0; i < 4; ++i)
            #pragma unroll
            for (int j = 0; j < 4; ++j) {
                acc[i][j] = __builtin_amdgcn_mfma_f32_16x16x32_f16(a[i], bh[j], acc[i][j], 0, 0, 0);
                acc[i][j] = __builtin_amdgcn_mfma_f32_16x16x32_f16(a[i], bl[j], acc[i][j], 0, 0, 0);
            }
        __syncthreads();   // readers done before next stage overwrites
    }
}

// grid (D/128, (B*S)/128, 3): z=0 -> Qh single; z=1 -> Kh+Kl; z=2 -> Vt hi/lo
__global__ __launch_bounds__(256) void qkv_mfma_kernel(
    const f16* __restrict__ xh,
    const f16* __restrict__ Wh, const f16* __restrict__ Wl,   // [3][D*D], x32
    const float* __restrict__ bq, const float* __restrict__ bk,
    const float* __restrict__ bv,
    f16* __restrict__ Qh, f16* __restrict__ Kh, f16* __restrict__ Kl,
    f16* __restrict__ Vth, f16* __restrict__ Vtl)
{
    __shared__ __align__(16) f16 smem[12288];
    const int z  = blockIdx.z;
    const int m0 = blockIdx.y * 128;
    const int n0 = blockIdx.x * 128;

    f32x4 acc[4][4];
    #pragma unroll
    for (int i = 0; i < 4; ++i)
        #pragma unroll
        for (int j = 0; j < 4; ++j) acc[i][j] = (f32x4){0.f, 0.f, 0.f, 0.f};

    const size_t wo = (size_t)z * 1024 * 1024;
    mfma_core2(xh, 1024, Wh + wo, Wl + wo, 1024, 1024, m0, n0, smem, acc);

    const float* bias = (z == 0) ? bq : (z == 1) ? bk : bv;
    const int lane = threadIdx.x & 63;
    const int wave = threadIdx.x >> 6;
    const int wm = (wave >> 1) * 64;
    const int wn = (wave & 1) * 64;
    const int col  = lane & 15;
    const int quad = lane >> 4;

    #pragma unroll
    for (int j = 0; j < 4; ++j) {
        const int gn = n0 + wn + j * 16 + col;
        const float bb = bias[gn];
        #pragma unroll
        for (int i = 0; i < 4; ++i) {
            #pragma unroll
            for (int r = 0; r < 4; ++r) {
                const int gm = m0 + wm + i * 16 + quad * 4 + r;
                const float v = acc[i][j][r] * 0.03125f + bb;  // /32: W prescale
                const f16 h = (f16)v;
                if (z == 0) {
                    Qh[(size_t)gm * 1024 + gn] = h;
                } else if (z == 1) {
                    const size_t idx = (size_t)gm * 1024 + gn;
                    Kh[idx] = h; Kl[idx] = (f16)(v - (float)h);
                } else {
                    const int b = gm >> 11, t = gm & 2047;
                    const size_t idx = (size_t)b * (1024 * 2048) + (size_t)gn * 2048 + t;
                    Vth[idx] = h; Vtl[idx] = (f16)(v - (float)h);
                }
            }
        }
    }
}

// grid (S/128, R/128, B); Sc chunk [B][R][S] fp32
__global__ __launch_bounds__(256) void scores_mfma_kernel(
    const f16* __restrict__ Qh, const f16* __restrict__ Kh,
    const f16* __restrict__ Kl, float* __restrict__ Sc,
    int r0, int R, float alpha)
{
    __shared__ __align__(16) f16 smem[12288];
    const int b  = blockIdx.z;
    const int m0 = blockIdx.y * 128;
    const int n0 = blockIdx.x * 128;

    f32x4 acc[4][4];
    #pragma unroll
    for (int i = 0; i < 4; ++i)
        #pragma unroll
        for (int j = 0; j < 4; ++j) acc[i][j] = (f32x4){0.f, 0.f, 0.f, 0.f};

    const size_t ao = ((size_t)b * 2048 + r0) * 1024;
    const size_t bo = (size_t)b * 2048 * 1024;
    mfma_core2(Qh + ao, 1024, Kh + bo, Kl + bo, 1024, 1024, m0, n0, smem, acc);

    const int lane = threadIdx.x & 63;
    const int wave = threadIdx.x >> 6;
    const int wm = (wave >> 1) * 64;
    const int wn = (wave & 1) * 64;
    const int col  = lane & 15;
    const int quad = lane >> 4;
    float* C = Sc + (size_t)b * R * 2048;

    #pragma unroll
    for (int i = 0; i < 4; ++i)
        #pragma unroll
        for (int r = 0; r < 4; ++r) {
            const int gm = m0 + wm + i * 16 + quad * 4 + r;
            #pragma unroll
            for (int j = 0; j < 4; ++j) {
                const int gn = n0 + wn + j * 16 + col;
                C[(size_t)gm * 2048 + gn] = alpha * acc[i][j][r];
            }
        }
}

// grid (D/128, R/128, B); Ph chunk [B][R][S] (x512), Vt [B][D][S] hi/lo
__global__ __launch_bounds__(256) void pv_mfma_kernel(
    const f16* __restrict__ Ph, const f16* __restrict__ Vth,
    const f16* __restrict__ Vtl, float* __restrict__ out, int r0, int R)
{
    __shared__ __align__(16) f16 smem[12288];
    const int b  = blockIdx.z;
    const int m0 = blockIdx.y * 128;
    const int n0 = blockIdx.x * 128;

    f32x4 acc[4][4];
    #pragma unroll
    for (int i = 0; i < 4; ++i)
        #pragma unroll
        for (int j = 0; j < 4; ++j) acc[i][j] = (f32x4){0.f, 0.f, 0.f, 0.f};

    const size_t ao = (size_t)b * R * 2048;
    const size_t bo = (size_t)b * 1024 * 2048;
    mfma_core2(Ph + ao, 2048, Vth + bo, Vtl + bo, 2048, 2048, m0, n0, smem, acc);

    const int lane = threadIdx.x & 63;
    const int wave = threadIdx.x >> 6;
    const int wm = (wave >> 1) * 64;
    const int wn = (wave & 1) * 64;
    const int col  = lane & 15;
    const int quad = lane >> 4;
    float* C = out + ((size_t)b * 2048 + r0) * 1024;

    #pragma unroll
    for (int i = 0; i < 4; ++i)
        #pragma unroll
        for (int r = 0; r < 4; ++r) {
            const int gm = m0 + wm + i * 16 + quad * 4 + r;
            #pragma unroll
            for (int j = 0; j < 4; ++j) {
                const int gn = n0 + wn + j * 16 + col;
                C[(size_t)gm * 1024 + gn] = acc[i][j][r] * 0.001953125f;  // /512
            }
        }
}

// one block per score row; fp32 Sc -> fp16 Ph = 512 * softmax(row)
__global__ __launch_bounds__(256) void softmax_p_kernel(
    const float* __restrict__ Sc, f16* __restrict__ Ph)
{
    const size_t base = (size_t)blockIdx.x * 2048;
    const int tid = threadIdx.x;
    float v[8];
    *(float4*)&v[0] = *(const float4*)(Sc + base + tid * 8);
    *(float4*)&v[4] = *(const float4*)(Sc + base + tid * 8 + 4);

    float m = v[0];
    #pragma unroll
    for (int i = 1; i < 8; ++i) m = fmaxf(m, v[i]);
    #pragma unroll
    for (int o = 32; o > 0; o >>= 1) m = fmaxf(m, __shfl_xor(m, o));

    __shared__ float sm[4], ssum[4];
    const int wave = tid >> 6;
    if ((tid & 63) == 0) sm[wave] = m;
    __syncthreads();
    m = fmaxf(fmaxf(sm[0], sm[1]), fmaxf(sm[2], sm[3]));

    float s = 0.0f;
    #pragma unroll
    for (int i = 0; i < 8; ++i) { v[i] = __expf(v[i] - m); s += v[i]; }
    #pragma unroll
    for (int o = 32; o > 0; o >>= 1) s += __shfl_xor(s, o);
    if ((tid & 63) == 0) ssum[wave] = s;
    __syncthreads();
    s = ssum[0] + ssum[1] + ssum[2] + ssum[3];
    const float inv = 512.0f / s;   // x512 prescale folded in

    f16x8 p;
    #pragma unroll
    for (int i = 0; i < 8; ++i) p[i] = (f16)(v[i] * inv);
    *(f16x8*)(Ph + base + tid * 8) = p;
}

// ===========================================================================
extern "C" void kernel_launch(void* const* d_in, const int* in_sizes, int n_in,
                              void* d_out, int out_size, void* d_ws, size_t ws_size,
                              hipStream_t stream)
{
    (void)in_sizes; (void)n_in; (void)out_size;
    const int Bn = 4, S = 2048, D = 1024;
    const float* x  = (const float*)d_in[0];
    const float* Wq = (const float*)d_in[1];
    const float* bq = (const float*)d_in[2];
    const float* Wk = (const float*)d_in[3];
    const float* bk = (const float*)d_in[4];
    const float* Wv = (const float*)d_in[5];
    const float* bv = (const float*)d_in[6];
    float* out = (float*)d_out;

    const size_t MB = 1024 * 1024;
    char* w = (char*)d_ws;
    // persistent fp16 planes (108 MiB):
    f16* xh  = (f16*)(w + 0 * MB);      // 16 MiB  [B*S][D]
    f16* Wh3 = (f16*)(w + 16 * MB);     // 6 MiB   [3][D*D]  (x32)
    f16* Wl3 = (f16*)(w + 22 * MB);     // 6 MiB
    f16* Qh  = (f16*)(w + 28 * MB);     // 16 MiB
    f16* Kh  = (f16*)(w + 44 * MB);     // 16 MiB
    f16* Kl  = (f16*)(w + 60 * MB);     // 16 MiB
    f16* Vth = (f16*)(w + 76 * MB);     // 16 MiB  [B][D][S]
    f16* Vtl = (f16*)(w + 92 * MB);     // 16 MiB
    // per-chunk: Sc fp32 at 108 MiB; Ph aliases dead x/W(/Q) region at 0.
    float* Sc = (float*)(w + 108 * MB);
    f16*   Ph = (f16*)(w + 0 * MB);

    // chunk rows R: full (needs 108+64=172 MiB; Ph 32 MiB over dead x/W/Qh),
    // else 1024 (needs 140; Ph 16 MiB over dead x), else 512 (needs 124).
    int R;
    if      (ws_size >= 172 * MB) R = 2048;
    else if (ws_size >= 140 * MB) R = 1024;
    else                          R = 512;

    // 1) splits
    split1_kernel<<<dim3(Bn * S * D / 4 / 256), 256, 0, stream>>>(
        x, xh, Bn * S * D / 4);
    split2_kernel<<<dim3(D * D / 4 / 256), 256, 0, stream>>>(
        Wq, Wh3 + 0 * D * D, Wl3 + 0 * D * D, D * D / 4, 32.0f);
    split2_kernel<<<dim3(D * D / 4 / 256), 256, 0, stream>>>(
        Wk, Wh3 + 1 * D * D, Wl3 + 1 * D * D, D * D / 4, 32.0f);
    split2_kernel<<<dim3(D * D / 4 / 256), 256, 0, stream>>>(
        Wv, Wh3 + 2 * D * D, Wl3 + 2 * D * D, D * D / 4, 32.0f);

    // 2) QKV projections
    qkv_mfma_kernel<<<dim3(D / 128, (Bn * S) / 128, 3), 256, 0, stream>>>(
        xh, Wh3, Wl3, bq, bk, bv, Qh, Kh, Kl, Vth, Vtl);

    // 3) attention
    const float scale = 1.0f / 32.0f;   // 1/sqrt(D)
    for (int r0 = 0; r0 < S; r0 += R) {
        scores_mfma_kernel<<<dim3(S / 128, R / 128, Bn), 256, 0, stream>>>(
            Qh, Kh, Kl, Sc, r0, R, scale);
        softmax_p_kernel<<<dim3(Bn * R), 256, 0, stream>>>(Sc, Ph);
        pv_mfma_kernel<<<dim3(D / 128, R / 128, Bn), 256, 0, stream>>>(
            Ph, Vth, Vtl, out, r0, R);
    }
}

// Round 4
// 297.009 us; speedup vs baseline: 5.0667x; 1.5046x over previous
//
#include <hip/hip_runtime.h>
#include <math.h>

// ---------------------------------------------------------------------------
// SimpleSelfAttention  B=4 S=2048 D=1024  fp32
// Round 4: pure single-plane fp16 MFMA everywhere (error budget: each stage
// contributes ~2^-12*sqrt(2K)*sigma ~ 3.4e-4; total max ~2e-3 < 6.25e-3).
// K-loop per K=32: 16 MFMA + 8 ds_read_b128 + 4 glds16  (m97-verified shape).
// V stored coalesced by qkv, separate LDS-tile transpose -> Vt[B][D][S].
// Sc kept fp16; P prescaled x512 (fp16 normal range), /512 in pv epilogue.
// ---------------------------------------------------------------------------

typedef _Float16 f16;
typedef _Float16 f16x8 __attribute__((ext_vector_type(8)));
typedef _Float16 f16x4 __attribute__((ext_vector_type(4)));
typedef float f32x4 __attribute__((ext_vector_type(4)));

__device__ __forceinline__ void glds16(const void* g, const void* l) {
    __builtin_amdgcn_global_load_lds(
        (const __attribute__((address_space(1))) void*)g,
        (__attribute__((address_space(3))) void*)l, 16, 0, 0);
}

// fp32 -> fp16 plane
__global__ __launch_bounds__(256) void cvt16_kernel(
    const float* __restrict__ in, f16* __restrict__ o, int n4)
{
    int i = blockIdx.x * 256 + threadIdx.x;
    if (i >= n4) return;
    float4 v = ((const float4*)in)[i];
    f16x4 h = { (f16)v.x, (f16)v.y, (f16)v.z, (f16)v.w };
    ((f16x4*)o)[i] = h;
}

// ---------------------------------------------------------------------------
// 128x128 NT fp16 MFMA core: C += A * B^T. A:[M][K], B:[N][K], both k-major
// fp16. 256 threads = 4 waves (2x2), wave = 64x64 = 4x4 16x16x32 tiles.
// LDS 16 KiB. K % 32 == 0.
// ---------------------------------------------------------------------------
__device__ __forceinline__ void mfma_core1(
    const f16* __restrict__ A, int lda,
    const f16* __restrict__ B, int ldb,
    int K, int m0, int n0, f16* sm, f32x4 acc[4][4])
{
    f16* sA = sm;            // [128][32]
    f16* sB = sm + 4096;

    const int tid  = threadIdx.x;
    const int lane = tid & 63;
    const int wave = tid >> 6;
    const int wm = (wave >> 1) * 64;
    const int wn = (wave & 1) * 64;
    const int lr = lane & 15;
    const int kq = lane >> 4;

    // staging: wave w covers tile rows [w*32, w*32+32)
    const int srow = wave * 32;
    const int grow = srow + (lane >> 2);
    const int gcol = (lane & 3) * 8;

    const f16* gA = A + (size_t)(m0 + grow) * lda + gcol;
    const f16* gB = B + (size_t)(n0 + grow) * ldb + gcol;
    const size_t rsA = (size_t)16 * lda;
    const size_t rsB = (size_t)16 * ldb;

    f16* lA = sA + srow * 32;
    f16* lB = sB + srow * 32;

    for (int k0 = 0; k0 < K; k0 += 32) {
        glds16(gA + k0,       lA);
        glds16(gA + k0 + rsA, lA + 512);
        glds16(gB + k0,       lB);
        glds16(gB + k0 + rsB, lB + 512);
        __syncthreads();   // drains vmcnt: LDS tiles ready

        f16x8 a[4], b[4];
        #pragma unroll
        for (int i = 0; i < 4; ++i) {
            a[i] = *(const f16x8*)&sA[(wm + i * 16 + lr) * 32 + kq * 8];
            b[i] = *(const f16x8*)&sB[(wn + i * 16 + lr) * 32 + kq * 8];
        }
        #pragma unroll
        for (int i = 0; i < 4; ++i)
            #pragma unroll
            for (int j = 0; j < 4; ++j)
                acc[i][j] = __builtin_amdgcn_mfma_f32_16x16x32_f16(a[i], b[j], acc[i][j], 0, 0, 0);
        __syncthreads();   // readers done before next stage overwrites
    }
}

// grid (D/128, (B*S)/128, 3): z=0 Q, z=1 K, z=2 V — all stored [B*S][D] f16
__global__ __launch_bounds__(256) void qkv_mfma_kernel(
    const f16* __restrict__ xh, const f16* __restrict__ Wh,  // [3][D*D]
    const float* __restrict__ bq, const float* __restrict__ bk,
    const float* __restrict__ bv,
    f16* __restrict__ Qh, f16* __restrict__ Kh, f16* __restrict__ Vh)
{
    __shared__ __align__(16) f16 smem[8192];
    const int z  = blockIdx.z;
    const int m0 = blockIdx.y * 128;
    const int n0 = blockIdx.x * 128;

    f32x4 acc[4][4];
    #pragma unroll
    for (int i = 0; i < 4; ++i)
        #pragma unroll
        for (int j = 0; j < 4; ++j) acc[i][j] = (f32x4){0.f, 0.f, 0.f, 0.f};

    mfma_core1(xh, 1024, Wh + (size_t)z * 1024 * 1024, 1024, 1024, m0, n0, smem, acc);

    const float* bias = (z == 0) ? bq : (z == 1) ? bk : bv;
    f16* C = (z == 0) ? Qh : (z == 1) ? Kh : Vh;
    const int lane = threadIdx.x & 63;
    const int wave = threadIdx.x >> 6;
    const int wm = (wave >> 1) * 64;
    const int wn = (wave & 1) * 64;
    const int col  = lane & 15;
    const int quad = lane >> 4;

    #pragma unroll
    for (int j = 0; j < 4; ++j) {
        const int gn = n0 + wn + j * 16 + col;
        const float bb = bias[gn];
        #pragma unroll
        for (int i = 0; i < 4; ++i)
            #pragma unroll
            for (int r = 0; r < 4; ++r) {
                const int gm = m0 + wm + i * 16 + quad * 4 + r;
                C[(size_t)gm * 1024 + gn] = (f16)(acc[i][j][r] + bb);
            }
    }
}

// V [B][S][D] -> Vt [B][D][S], 64x64 LDS tiles. grid (S/64, D/64, B)
__global__ __launch_bounds__(256) void vtrans_kernel(
    const f16* __restrict__ V, f16* __restrict__ Vt)
{
    __shared__ f16 t[64][72];
    const int b  = blockIdx.z;
    const int s0 = blockIdx.x * 64;
    const int d0 = blockIdx.y * 64;
    const int tid = threadIdx.x;

    const int r  = tid >> 3;          // 0..31
    const int c8 = (tid & 7) * 8;
    const f16* src = V + ((size_t)b * 2048 + s0) * 1024 + d0;
    *(f16x8*)&t[r][c8]      = *(const f16x8*)(src + (size_t)r * 1024 + c8);
    *(f16x8*)&t[r + 32][c8] = *(const f16x8*)(src + (size_t)(r + 32) * 1024 + c8);
    __syncthreads();

    // out: row d-local = tid>>2 (0..63), s-cols (tid&3)*16 .. +16
    const int dl  = tid >> 2;
    const int sl0 = (tid & 3) * 16;
    f16* dst = Vt + ((size_t)b * 1024 + d0 + dl) * 2048 + s0 + sl0;
    f16 buf[16];
    #pragma unroll
    for (int u = 0; u < 16; ++u) buf[u] = t[sl0 + u][dl];
    *(f16x8*)dst       = *(f16x8*)&buf[0];
    *(f16x8*)(dst + 8) = *(f16x8*)&buf[8];
}

// grid (S/128, R/128, B); Sc chunk [B][R][S] fp16 (scaled scores)
__global__ __launch_bounds__(256) void scores_mfma_kernel(
    const f16* __restrict__ Qh, const f16* __restrict__ Kh,
    f16* __restrict__ Sc, int r0, int R, float alpha)
{
    __shared__ __align__(16) f16 smem[8192];
    const int b  = blockIdx.z;
    const int m0 = blockIdx.y * 128;
    const int n0 = blockIdx.x * 128;

    f32x4 acc[4][4];
    #pragma unroll
    for (int i = 0; i < 4; ++i)
        #pragma unroll
        for (int j = 0; j < 4; ++j) acc[i][j] = (f32x4){0.f, 0.f, 0.f, 0.f};

    const size_t ao = ((size_t)b * 2048 + r0) * 1024;
    const size_t bo = (size_t)b * 2048 * 1024;
    mfma_core1(Qh + ao, 1024, Kh + bo, 1024, 1024, m0, n0, smem, acc);

    const int lane = threadIdx.x & 63;
    const int wave = threadIdx.x >> 6;
    const int wm = (wave >> 1) * 64;
    const int wn = (wave & 1) * 64;
    const int col  = lane & 15;
    const int quad = lane >> 4;
    f16* C = Sc + (size_t)b * R * 2048;

    #pragma unroll
    for (int i = 0; i < 4; ++i)
        #pragma unroll
        for (int r = 0; r < 4; ++r) {
            const int gm = m0 + wm + i * 16 + quad * 4 + r;
            #pragma unroll
            for (int j = 0; j < 4; ++j) {
                const int gn = n0 + wn + j * 16 + col;
                C[(size_t)gm * 2048 + gn] = (f16)(alpha * acc[i][j][r]);
            }
        }
}

// grid (D/128, R/128, B); Ph chunk [B][R][S] (x512), Vt [B][D][S]
__global__ __launch_bounds__(256) void pv_mfma_kernel(
    const f16* __restrict__ Ph, const f16* __restrict__ Vt,
    float* __restrict__ out, int r0, int R)
{
    __shared__ __align__(16) f16 smem[8192];
    const int b  = blockIdx.z;
    const int m0 = blockIdx.y * 128;
    const int n0 = blockIdx.x * 128;

    f32x4 acc[4][4];
    #pragma unroll
    for (int i = 0; i < 4; ++i)
        #pragma unroll
        for (int j = 0; j < 4; ++j) acc[i][j] = (f32x4){0.f, 0.f, 0.f, 0.f};

    const size_t ao = (size_t)b * R * 2048;
    const size_t bo = (size_t)b * 1024 * 2048;
    mfma_core1(Ph + ao, 2048, Vt + bo, 2048, 2048, m0, n0, smem, acc);

    const int lane = threadIdx.x & 63;
    const int wave = threadIdx.x >> 6;
    const int wm = (wave >> 1) * 64;
    const int wn = (wave & 1) * 64;
    const int col  = lane & 15;
    const int quad = lane >> 4;
    float* C = out + ((size_t)b * 2048 + r0) * 1024;

    #pragma unroll
    for (int i = 0; i < 4; ++i)
        #pragma unroll
        for (int r = 0; r < 4; ++r) {
            const int gm = m0 + wm + i * 16 + quad * 4 + r;
            #pragma unroll
            for (int j = 0; j < 4; ++j) {
                const int gn = n0 + wn + j * 16 + col;
                C[(size_t)gm * 1024 + gn] = acc[i][j][r] * 0.001953125f;  // /512
            }
        }
}

// one block per score row; fp16 Sc -> fp16 Ph = 512 * softmax(row)
__global__ __launch_bounds__(256) void softmax_p_kernel(
    const f16* __restrict__ Sc, f16* __restrict__ Ph)
{
    const size_t base = (size_t)blockIdx.x * 2048;
    const int tid = threadIdx.x;
    f16x8 sv = *(const f16x8*)(Sc + base + tid * 8);
    float v[8];
    #pragma unroll
    for (int i = 0; i < 8; ++i) v[i] = (float)sv[i];

    float m = v[0];
    #pragma unroll
    for (int i = 1; i < 8; ++i) m = fmaxf(m, v[i]);
    #pragma unroll
    for (int o = 32; o > 0; o >>= 1) m = fmaxf(m, __shfl_xor(m, o));

    __shared__ float sm[4], ssum[4];
    const int wave = tid >> 6;
    if ((tid & 63) == 0) sm[wave] = m;
    __syncthreads();
    m = fmaxf(fmaxf(sm[0], sm[1]), fmaxf(sm[2], sm[3]));

    float s = 0.0f;
    #pragma unroll
    for (int i = 0; i < 8; ++i) { v[i] = __expf(v[i] - m); s += v[i]; }
    #pragma unroll
    for (int o = 32; o > 0; o >>= 1) s += __shfl_xor(s, o);
    if ((tid & 63) == 0) ssum[wave] = s;
    __syncthreads();
    s = ssum[0] + ssum[1] + ssum[2] + ssum[3];
    const float inv = 512.0f / s;   // x512 prescale folded in

    f16x8 p;
    #pragma unroll
    for (int i = 0; i < 8; ++i) p[i] = (f16)(v[i] * inv);
    *(f16x8*)(Ph + base + tid * 8) = p;
}

// ===========================================================================
extern "C" void kernel_launch(void* const* d_in, const int* in_sizes, int n_in,
                              void* d_out, int out_size, void* d_ws, size_t ws_size,
                              hipStream_t stream)
{
    (void)in_sizes; (void)n_in; (void)out_size;
    const int Bn = 4, S = 2048, D = 1024;
    const float* x  = (const float*)d_in[0];
    const float* Wq = (const float*)d_in[1];
    const float* bq = (const float*)d_in[2];
    const float* Wk = (const float*)d_in[3];
    const float* bk = (const float*)d_in[4];
    const float* Wv = (const float*)d_in[5];
    const float* bv = (const float*)d_in[6];
    float* out = (float*)d_out;

    const size_t MB = 1024 * 1024;
    char* w = (char*)d_ws;
    f16* xh  = (f16*)(w + 0 * MB);      // 16 MiB  [B*S][D]
    f16* Wh3 = (f16*)(w + 16 * MB);     // 6 MiB   [3][D*D]
    f16* Qh  = (f16*)(w + 22 * MB);     // 16 MiB
    f16* Kh  = (f16*)(w + 38 * MB);     // 16 MiB
    f16* Vh  = (f16*)(w + 54 * MB);     // 16 MiB  [B][S][D]
    f16* Vt  = (f16*)(w + 70 * MB);     // 16 MiB  [B][D][S]
    f16* Sc  = (f16*)(w + 86 * MB);     // chunk scores f16 [B][R][S]
    f16* Ph;                            // chunk probs f16 [B][R][S]

    // R tiers: 2048 needs 86+32+32=150 MiB; 1024: Sc 16 @86, Ph 16 aliases
    // dead xh/W region (22 MiB) -> 102; 512: 8+8 -> 94.
    int R;
    if (ws_size >= 150 * MB) { R = 2048; Ph = (f16*)(w + 118 * MB); }
    else if (ws_size >= 102 * MB) { R = 1024; Ph = (f16*)(w + 0 * MB); }
    else { R = 512; Ph = (f16*)(w + 0 * MB); }

    // 1) fp32 -> fp16 conversions
    cvt16_kernel<<<dim3(Bn * S * D / 4 / 256), 256, 0, stream>>>(x, xh, Bn * S * D / 4);
    cvt16_kernel<<<dim3(3 * D * D / 4 / 256), 256, 0, stream>>>(Wq, Wh3 + 0 * D * D, D * D / 4);
    cvt16_kernel<<<dim3(3 * D * D / 4 / 256), 256, 0, stream>>>(Wk, Wh3 + 1 * D * D, D * D / 4);
    cvt16_kernel<<<dim3(3 * D * D / 4 / 256), 256, 0, stream>>>(Wv, Wh3 + 2 * D * D, D * D / 4);

    // 2) QKV projections (V stored row-major, then transposed)
    qkv_mfma_kernel<<<dim3(D / 128, (Bn * S) / 128, 3), 256, 0, stream>>>(
        xh, Wh3, bq, bk, bv, Qh, Kh, Vh);
    vtrans_kernel<<<dim3(S / 64, D / 64, Bn), 256, 0, stream>>>(Vh, Vt);

    // 3) attention
    const float scale = 1.0f / 32.0f;   // 1/sqrt(D)
    for (int r0 = 0; r0 < S; r0 += R) {
        scores_mfma_kernel<<<dim3(S / 128, R / 128, Bn), 256, 0, stream>>>(
            Qh, Kh, Sc, r0, R, scale);
        softmax_p_kernel<<<dim3(Bn * R), 256, 0, stream>>>(Sc, Ph);
        pv_mfma_kernel<<<dim3(D / 128, R / 128, Bn), 256, 0, stream>>>(
            Ph, Vt, out, r0, R);
    }
}